// Round 1
// baseline (2398.616 us; speedup 1.0000x reference)
//
#include <hip/hip_runtime.h>

// ---------------------------------------------------------------------------
// CrowdGNN: 2-layer GCN on N=500k nodes, E=8M edges (+ self loops).
// out = GCNConv2( relu(GCNConv1(x)) )
// Trick: linear layer commutes with scatter:
//   segment_sum(norm * (x@W)[src]) == segment_sum(norm * x[src]) @ W
// -> layer1 scatters 4 floats/edge, layer2 scatters 1 float/edge.
// Self loops (w=1, norm=1/deg) handled analytically per node.
// ---------------------------------------------------------------------------

// Detect whether edge_index buffer is int64 (odd 32-bit words all zero since
// values < 2^31) or int32. Single block; writes flag (1 => int64).
__global__ __launch_bounds__(1024)
void k_detect(const unsigned int* __restrict__ idx_words, int nCheck, int* flag) {
    __shared__ int cnt;
    if (threadIdx.x == 0) cnt = 0;
    __syncthreads();
    int local = 0;
    for (int i = threadIdx.x; i < nCheck; i += blockDim.x)
        local += (idx_words[2 * i + 1] != 0u) ? 1 : 0;
    if (local) atomicAdd(&cnt, local);
    __syncthreads();
    if (threadIdx.x == 0) *flag = (cnt < 8) ? 1 : 0;
}

// deg[n] = 1.0 (self-loop weight)
__global__ __launch_bounds__(256)
void k_init(float* __restrict__ deg, int N) {
    int i = blockIdx.x * blockDim.x + threadIdx.x;
    if (i < N) deg[i] = 1.0f;
}

// deg[dst[e]] += w[e]
__global__ __launch_bounds__(256)
void k_deg(const void* __restrict__ idx, const float* __restrict__ ew,
           float* __restrict__ deg, int E, const int* __restrict__ flag) {
    const bool is64 = (*flag != 0);
    const int stride = gridDim.x * blockDim.x;
    for (int e = blockIdx.x * blockDim.x + threadIdx.x; e < E; e += stride) {
        int d = is64 ? (int)((const long long*)idx)[(long long)E + e]
                     : ((const int*)idx)[E + e];
        atomicAdd(deg + d, ew[e]);
    }
}

// dinv = rsqrt(deg) (in place); accx[n] = x[n] * dinv^2  (self-loop term)
__global__ __launch_bounds__(256)
void k_dinv_accx(float* __restrict__ deg_dinv, const float4* __restrict__ x,
                 float4* __restrict__ accx, int N) {
    int n = blockIdx.x * blockDim.x + threadIdx.x;
    if (n >= N) return;
    float dg = deg_dinv[n];
    float di = (dg > 0.0f) ? rsqrtf(dg) : 0.0f;
    deg_dinv[n] = di;
    float sn = di * di;
    float4 xv = x[n];
    accx[n] = make_float4(xv.x * sn, xv.y * sn, xv.z * sn, xv.w * sn);
}

// accx[dst] += (dinv[src]*w*dinv[dst]) * x[src]   (4 atomics/edge)
__global__ __launch_bounds__(256)
void k_scatter1(const void* __restrict__ idx, const float* __restrict__ ew,
                const float* __restrict__ dinv, const float4* __restrict__ x,
                float* __restrict__ accx, int E, const int* __restrict__ flag) {
    const bool is64 = (*flag != 0);
    const int stride = gridDim.x * blockDim.x;
    for (int e = blockIdx.x * blockDim.x + threadIdx.x; e < E; e += stride) {
        int s, d;
        if (is64) {
            const long long* p = (const long long*)idx;
            s = (int)p[e]; d = (int)p[(long long)E + e];
        } else {
            const int* p = (const int*)idx;
            s = p[e]; d = p[E + e];
        }
        float nm = dinv[s] * ew[e] * dinv[d];
        float4 xv = x[s];
        float* dp = accx + (size_t)d * 4;
        atomicAdd(dp + 0, nm * xv.x);
        atomicAdd(dp + 1, nm * xv.y);
        atomicAdd(dp + 2, nm * xv.z);
        atomicAdd(dp + 3, nm * xv.w);
    }
}

// h = relu(accx @ W1 + b1); s2 = h @ W2; out = s2*dinv^2 + b2 (self-loop + bias)
__global__ __launch_bounds__(256)
void k_node2(const float4* __restrict__ accx, const float* __restrict__ dinv,
             const float* __restrict__ W1, const float* __restrict__ b1,
             const float* __restrict__ W2, const float* __restrict__ b2,
             float* __restrict__ s2, float* __restrict__ out, int N) {
    __shared__ float sW1[64], sb1[16], sW2[16];
    if (threadIdx.x < 64) sW1[threadIdx.x] = W1[threadIdx.x];
    if (threadIdx.x < 16) {
        sb1[threadIdx.x] = b1[threadIdx.x];
        sW2[threadIdx.x] = W2[threadIdx.x];
    }
    __syncthreads();
    int n = blockIdx.x * blockDim.x + threadIdx.x;
    if (n >= N) return;
    float bb2 = b2[0];
    float4 a = accx[n];
    float acc = 0.0f;
#pragma unroll
    for (int k = 0; k < 16; ++k) {
        float h = a.x * sW1[k] + a.y * sW1[16 + k] + a.z * sW1[32 + k]
                + a.w * sW1[48 + k] + sb1[k];
        h = fmaxf(h, 0.0f);
        acc += h * sW2[k];
    }
    s2[n] = acc;
    float di = dinv[n];
    out[n] = acc * di * di + bb2;
}

// out[dst] += (dinv[src]*w*dinv[dst]) * s2[src]   (1 atomic/edge)
__global__ __launch_bounds__(256)
void k_scatter2(const void* __restrict__ idx, const float* __restrict__ ew,
                const float* __restrict__ dinv, const float* __restrict__ s2,
                float* __restrict__ out, int E, const int* __restrict__ flag) {
    const bool is64 = (*flag != 0);
    const int stride = gridDim.x * blockDim.x;
    for (int e = blockIdx.x * blockDim.x + threadIdx.x; e < E; e += stride) {
        int s, d;
        if (is64) {
            const long long* p = (const long long*)idx;
            s = (int)p[e]; d = (int)p[(long long)E + e];
        } else {
            const int* p = (const int*)idx;
            s = p[e]; d = p[E + e];
        }
        float nm = dinv[s] * ew[e] * dinv[d];
        atomicAdd(out + d, nm * s2[s]);
    }
}

extern "C" void kernel_launch(void* const* d_in, const int* in_sizes, int n_in,
                              void* d_out, int out_size, void* d_ws, size_t ws_size,
                              hipStream_t stream) {
    const float* x   = (const float*)d_in[0];
    const void*  eix = d_in[1];
    const float* ew  = (const float*)d_in[2];
    const float* W1  = (const float*)d_in[3];
    const float* b1  = (const float*)d_in[4];
    const float* W2  = (const float*)d_in[5];
    const float* b2  = (const float*)d_in[6];
    float* out = (float*)d_out;

    const int N = in_sizes[0] / 4;   // x is [N,4]
    const int E = in_sizes[2];       // edge_weight is [E]

    // ws layout (floats): deg/dinv [N] | accx [4N] | s2 [N] | flag (int)
    float* deg  = (float*)d_ws;
    float* accx = deg + N;
    float* s2   = accx + (size_t)4 * N;
    int*   flag = (int*)(s2 + N);

    const int nb_n = (N + 255) / 256;
    const int nb_e = min((E + 255) / 256, 16384);
    const int nCheck = (E < 65536) ? E : 65536;

    k_init<<<nb_n, 256, 0, stream>>>(deg, N);
    k_detect<<<1, 1024, 0, stream>>>((const unsigned int*)eix, nCheck, flag);
    k_deg<<<nb_e, 256, 0, stream>>>(eix, ew, deg, E, flag);
    k_dinv_accx<<<nb_n, 256, 0, stream>>>(deg, (const float4*)x, (float4*)accx, N);
    k_scatter1<<<nb_e, 256, 0, stream>>>(eix, ew, deg, (const float4*)x, accx, E, flag);
    k_node2<<<nb_n, 256, 0, stream>>>((const float4*)accx, deg, W1, b1, W2, b2, s2, out, N);
    k_scatter2<<<nb_e, 256, 0, stream>>>(eix, ew, deg, s2, out, E, flag);
}

// Round 2
// 1351.691 us; speedup vs baseline: 1.7745x; 1.7745x over previous
//
#include <hip/hip_runtime.h>

// ---------------------------------------------------------------------------
// CrowdGNN: 2-layer GCN, N=500k nodes, E=8M edges (+ implicit self loops).
// Round-2 strategy: global atomics are rate-bound (~20G/s, memory-side RMW),
// so build a capacity-padded in-edge bucket table with ONE atomic per edge,
// then do atomic-free gather passes for deg, layer1(+fused MLP), layer2.
//   slots[dst*cap + pos] = (src, w),  pos = atomicAdd(cnt[dst], 1)
// Self loops handled analytically (deg = 1 + sum w; self term = val/deg).
// Falls back to direct-atomic scatter if ws_size can't hold the table.
// ---------------------------------------------------------------------------

// Detect int64 vs int32 edge_index: if int64 (values < 2^31), odd words are 0.
__global__ __launch_bounds__(1024)
void k_detect(const unsigned int* __restrict__ idx_words, int nCheck, int* flag) {
    __shared__ int cnt;
    if (threadIdx.x == 0) cnt = 0;
    __syncthreads();
    int local = 0;
    for (int i = threadIdx.x; i < nCheck; i += blockDim.x)
        local += (idx_words[2 * i + 1] != 0u) ? 1 : 0;
    if (local) atomicAdd(&cnt, local);
    __syncthreads();
    if (threadIdx.x == 0) *flag = (cnt < 8) ? 1 : 0;
}

__global__ __launch_bounds__(256)
void k_zero(int* __restrict__ p, int n) {
    int i = blockIdx.x * blockDim.x + threadIdx.x;
    if (i < n) p[i] = 0;
}

// One atomic per edge: reserve slot in dst bucket, store (src, w).
__global__ __launch_bounds__(256)
void k_place(const void* __restrict__ idx, const float* __restrict__ ew,
             int* __restrict__ cnt, int2* __restrict__ slots,
             int E, int cap, const int* __restrict__ flag) {
    const bool is64 = (*flag != 0);
    const int stride = gridDim.x * blockDim.x;
    for (int e = blockIdx.x * blockDim.x + threadIdx.x; e < E; e += stride) {
        int s, d;
        if (is64) {
            const long long* p = (const long long*)idx;
            s = (int)p[e]; d = (int)p[(long long)E + e];
        } else {
            const int* p = (const int*)idx;
            s = p[e]; d = p[E + e];
        }
        int pos = atomicAdd(cnt + d, 1);
        if (pos < cap)  // Poisson(16), cap>=48 => overflow prob ~1e-15/node
            slots[(size_t)d * cap + pos] = make_int2(s, __float_as_int(ew[e]));
    }
}

// deg[n] = 1 + sum(w of in-edges); dinv = rsqrt(deg)
__global__ __launch_bounds__(256)
void k_dinv(const int* __restrict__ cnt, const int2* __restrict__ slots,
            float* __restrict__ dinv, int N, int cap) {
    int n = blockIdx.x * blockDim.x + threadIdx.x;
    if (n >= N) return;
    int c = min(cnt[n], cap);
    const int2* sp = slots + (size_t)n * cap;
    float deg = 1.0f;
    for (int j = 0; j < c; ++j) deg += __int_as_float(sp[j].y);
    dinv[n] = rsqrtf(deg);
}

// Layer-1 aggregation in 4-dim input domain + fused MLP:
// acc = x[n]*dinv^2 + sum nm*x[src];  h=relu(acc@W1+b1);  s2[n]=h@W2
__global__ __launch_bounds__(256)
void k_gather1(const int* __restrict__ cnt, const int2* __restrict__ slots,
               const float* __restrict__ dinv, const float4* __restrict__ x,
               const float* __restrict__ W1, const float* __restrict__ b1,
               const float* __restrict__ W2, float* __restrict__ s2,
               int N, int cap) {
    __shared__ float sW1[64], sb1[16], sW2[16];
    if (threadIdx.x < 64) sW1[threadIdx.x] = W1[threadIdx.x];
    if (threadIdx.x < 16) {
        sb1[threadIdx.x] = b1[threadIdx.x];
        sW2[threadIdx.x] = W2[threadIdx.x];
    }
    __syncthreads();
    int n = blockIdx.x * blockDim.x + threadIdx.x;
    if (n >= N) return;
    float di = dinv[n];
    float4 xv = x[n];
    float sn = di * di;
    float ax = xv.x * sn, ay = xv.y * sn, az = xv.z * sn, aw = xv.w * sn;
    int c = min(cnt[n], cap);
    const int2* sp = slots + (size_t)n * cap;
    for (int j = 0; j < c; ++j) {
        int2 pk = sp[j];
        int s = pk.x;
        float nm = dinv[s] * __int_as_float(pk.y) * di;
        float4 xs = x[s];
        ax += nm * xs.x; ay += nm * xs.y; az += nm * xs.z; aw += nm * xs.w;
    }
    float acc = 0.0f;
#pragma unroll
    for (int k = 0; k < 16; ++k) {
        float h = ax * sW1[k] + ay * sW1[16 + k] + az * sW1[32 + k]
                + aw * sW1[48 + k] + sb1[k];
        acc += fmaxf(h, 0.0f) * sW2[k];
    }
    s2[n] = acc;
}

// Layer-2 aggregation (1-dim): out[n] = s2[n]*dinv^2 + b2 + sum nm*s2[src]
__global__ __launch_bounds__(256)
void k_gather2(const int* __restrict__ cnt, const int2* __restrict__ slots,
               const float* __restrict__ dinv, const float* __restrict__ s2,
               const float* __restrict__ b2, float* __restrict__ out,
               int N, int cap) {
    int n = blockIdx.x * blockDim.x + threadIdx.x;
    if (n >= N) return;
    float di = dinv[n];
    float o = s2[n] * di * di + b2[0];
    int c = min(cnt[n], cap);
    const int2* sp = slots + (size_t)n * cap;
    for (int j = 0; j < c; ++j) {
        int2 pk = sp[j];
        o += dinv[pk.x] * __int_as_float(pk.y) * di * s2[pk.x];
    }
    out[n] = o;
}

// ------------------------- fallback (round-1) path -------------------------
__global__ __launch_bounds__(256)
void k_init(float* __restrict__ deg, int N) {
    int i = blockIdx.x * blockDim.x + threadIdx.x;
    if (i < N) deg[i] = 1.0f;
}

__global__ __launch_bounds__(256)
void k_deg(const void* __restrict__ idx, const float* __restrict__ ew,
           float* __restrict__ deg, int E, const int* __restrict__ flag) {
    const bool is64 = (*flag != 0);
    const int stride = gridDim.x * blockDim.x;
    for (int e = blockIdx.x * blockDim.x + threadIdx.x; e < E; e += stride) {
        int d = is64 ? (int)((const long long*)idx)[(long long)E + e]
                     : ((const int*)idx)[E + e];
        atomicAdd(deg + d, ew[e]);
    }
}

__global__ __launch_bounds__(256)
void k_dinv_accx(float* __restrict__ deg_dinv, const float4* __restrict__ x,
                 float4* __restrict__ accx, int N) {
    int n = blockIdx.x * blockDim.x + threadIdx.x;
    if (n >= N) return;
    float dg = deg_dinv[n];
    float di = (dg > 0.0f) ? rsqrtf(dg) : 0.0f;
    deg_dinv[n] = di;
    float sn = di * di;
    float4 xv = x[n];
    accx[n] = make_float4(xv.x * sn, xv.y * sn, xv.z * sn, xv.w * sn);
}

__global__ __launch_bounds__(256)
void k_scatter1(const void* __restrict__ idx, const float* __restrict__ ew,
                const float* __restrict__ dinv, const float4* __restrict__ x,
                float* __restrict__ accx, int E, const int* __restrict__ flag) {
    const bool is64 = (*flag != 0);
    const int stride = gridDim.x * blockDim.x;
    for (int e = blockIdx.x * blockDim.x + threadIdx.x; e < E; e += stride) {
        int s, d;
        if (is64) {
            const long long* p = (const long long*)idx;
            s = (int)p[e]; d = (int)p[(long long)E + e];
        } else {
            const int* p = (const int*)idx;
            s = p[e]; d = p[E + e];
        }
        float nm = dinv[s] * ew[e] * dinv[d];
        float4 xv = x[s];
        float* dp = accx + (size_t)d * 4;
        atomicAdd(dp + 0, nm * xv.x);
        atomicAdd(dp + 1, nm * xv.y);
        atomicAdd(dp + 2, nm * xv.z);
        atomicAdd(dp + 3, nm * xv.w);
    }
}

__global__ __launch_bounds__(256)
void k_node2(const float4* __restrict__ accx, const float* __restrict__ dinv,
             const float* __restrict__ W1, const float* __restrict__ b1,
             const float* __restrict__ W2, const float* __restrict__ b2,
             float* __restrict__ s2, float* __restrict__ out, int N) {
    __shared__ float sW1[64], sb1[16], sW2[16];
    if (threadIdx.x < 64) sW1[threadIdx.x] = W1[threadIdx.x];
    if (threadIdx.x < 16) {
        sb1[threadIdx.x] = b1[threadIdx.x];
        sW2[threadIdx.x] = W2[threadIdx.x];
    }
    __syncthreads();
    int n = blockIdx.x * blockDim.x + threadIdx.x;
    if (n >= N) return;
    float bb2 = b2[0];
    float4 a = accx[n];
    float acc = 0.0f;
#pragma unroll
    for (int k = 0; k < 16; ++k) {
        float h = a.x * sW1[k] + a.y * sW1[16 + k] + a.z * sW1[32 + k]
                + a.w * sW1[48 + k] + sb1[k];
        acc += fmaxf(h, 0.0f) * sW2[k];
    }
    s2[n] = acc;
    float di = dinv[n];
    out[n] = acc * di * di + bb2;
}

__global__ __launch_bounds__(256)
void k_scatter2(const void* __restrict__ idx, const float* __restrict__ ew,
                const float* __restrict__ dinv, const float* __restrict__ s2,
                float* __restrict__ out, int E, const int* __restrict__ flag) {
    const bool is64 = (*flag != 0);
    const int stride = gridDim.x * blockDim.x;
    for (int e = blockIdx.x * blockDim.x + threadIdx.x; e < E; e += stride) {
        int s, d;
        if (is64) {
            const long long* p = (const long long*)idx;
            s = (int)p[e]; d = (int)p[(long long)E + e];
        } else {
            const int* p = (const int*)idx;
            s = p[e]; d = p[E + e];
        }
        float nm = dinv[s] * ew[e] * dinv[d];
        atomicAdd(out + d, nm * s2[s]);
    }
}

// ---------------------------------------------------------------------------
extern "C" void kernel_launch(void* const* d_in, const int* in_sizes, int n_in,
                              void* d_out, int out_size, void* d_ws, size_t ws_size,
                              hipStream_t stream) {
    const float* x   = (const float*)d_in[0];
    const void*  eix = d_in[1];
    const float* ew  = (const float*)d_in[2];
    const float* W1  = (const float*)d_in[3];
    const float* b1  = (const float*)d_in[4];
    const float* W2  = (const float*)d_in[5];
    const float* b2  = (const float*)d_in[6];
    float* out = (float*)d_out;

    const int N = in_sizes[0] / 4;   // x is [N,4]
    const int E = in_sizes[2];       // edge_weight is [E]

    const int nb_n = (N + 255) / 256;
    const int nb_e = min((E + 255) / 256, 16384);
    const int nCheck = (E < 65536) ? E : 65536;

    // bucket-table path needs: slots N*cap*8B + cnt/dinv/s2 (12B*N) + flag
    long long avail = (long long)ws_size - ((long long)N * 12 + 256);
    long long capll = (avail > 0) ? avail / ((long long)N * 8) : 0;
    if (capll > 64) capll = 64;

    if (capll >= 48) {
        const int cap = (int)capll;
        int2*  slots = (int2*)d_ws;
        int*   cnt   = (int*)(slots + (size_t)N * cap);
        float* dinv  = (float*)(cnt + N);
        float* s2    = dinv + N;
        int*   flag  = (int*)(s2 + N);

        k_zero<<<nb_n, 256, 0, stream>>>(cnt, N);
        k_detect<<<1, 1024, 0, stream>>>((const unsigned int*)eix, nCheck, flag);
        k_place<<<nb_e, 256, 0, stream>>>(eix, ew, cnt, slots, E, cap, flag);
        k_dinv<<<nb_n, 256, 0, stream>>>(cnt, slots, dinv, N, cap);
        k_gather1<<<nb_n, 256, 0, stream>>>(cnt, slots, dinv, (const float4*)x,
                                            W1, b1, W2, s2, N, cap);
        k_gather2<<<nb_n, 256, 0, stream>>>(cnt, slots, dinv, s2, b2, out, N, cap);
    } else {
        // fallback: direct atomic scatter (round-1)
        float* deg  = (float*)d_ws;
        float* accx = deg + N;
        float* s2   = accx + (size_t)4 * N;
        int*   flag = (int*)(s2 + N);

        k_init<<<nb_n, 256, 0, stream>>>(deg, N);
        k_detect<<<1, 1024, 0, stream>>>((const unsigned int*)eix, nCheck, flag);
        k_deg<<<nb_e, 256, 0, stream>>>(eix, ew, deg, E, flag);
        k_dinv_accx<<<nb_n, 256, 0, stream>>>(deg, (const float4*)x, (float4*)accx, N);
        k_scatter1<<<nb_e, 256, 0, stream>>>(eix, ew, deg, (const float4*)x, accx, E, flag);
        k_node2<<<nb_n, 256, 0, stream>>>((const float4*)accx, deg, W1, b1, W2, b2, s2, out, N);
        k_scatter2<<<nb_e, 256, 0, stream>>>(eix, ew, deg, s2, out, E, flag);
    }
}

// Round 3
// 390.839 us; speedup vs baseline: 6.1371x; 3.4584x over previous
//
#include <hip/hip_runtime.h>

// ---------------------------------------------------------------------------
// CrowdGNN: 2-layer GCN, N=500k nodes, E=8M edges (+ implicit self loops).
// Round-3: eliminate per-edge global atomics entirely.
//  1) k_partition: bin edges by dst>>9 with LDS-ranked two-phase binning:
//     rank within bin via LDS atomics, ONE global atomic per (block,bin)
//     (~0.5M instead of 8M), payload (dstLow<<23|src, w) written to
//     bin*cap + base + rank (clustered -> L2 write combining).
//  2) per-bin workgroups accumulate deg / layer1 / layer2 in LDS (512 nodes),
//     atomic-free in global. Algebra rescaled:
//       y[m] = dinv[m]*x[m];  aggr1(n) = di*(y[n] + sum_e w*y[s])
//       z[n] = dinv[n]*MLP(aggr1);  out[n] = di*(z[n] + sum_e w*z[s]) + b2
// ---------------------------------------------------------------------------

#define NPB_SHIFT 9
#define NPB 512
#define MAX_BINS 2048
#define PART_THREADS 1024
#define PART_EPT 16

// Detect int64 vs int32 edge_index: int64 values < 2^31 => odd words all zero.
__global__ __launch_bounds__(1024)
void k_detect(const unsigned int* __restrict__ idx_words, int nCheck, int* flag) {
    __shared__ int cnt;
    if (threadIdx.x == 0) cnt = 0;
    __syncthreads();
    int local = 0;
    for (int i = threadIdx.x; i < nCheck; i += blockDim.x)
        local += (idx_words[2 * i + 1] != 0u) ? 1 : 0;
    if (local) atomicAdd(&cnt, local);
    __syncthreads();
    if (threadIdx.x == 0) *flag = (cnt < 8) ? 1 : 0;
}

__global__ __launch_bounds__(256)
void k_zero(int* __restrict__ p, int n) {
    int i = blockIdx.x * blockDim.x + threadIdx.x;
    if (i < n) p[i] = 0;
}

// Two-phase binning partition. Block = 1024 thr x 16 edges.
__global__ __launch_bounds__(PART_THREADS)
void k_partition(const void* __restrict__ idx, const float* __restrict__ ew,
                 int* __restrict__ gCnt, unsigned long long* __restrict__ slots,
                 int E, int B, int cap, const int* __restrict__ flag) {
    __shared__ int lcnt[MAX_BINS];
    __shared__ int lbase[MAX_BINS];
    const bool is64 = (*flag != 0);
    for (int i = threadIdx.x; i < B; i += PART_THREADS) lcnt[i] = 0;
    __syncthreads();

    const int base_e = blockIdx.x * (PART_EPT * PART_THREADS);
    unsigned long long pay[PART_EPT];
    int binrank[PART_EPT];

#pragma unroll
    for (int i = 0; i < PART_EPT; ++i) {
        int e = base_e + i * PART_THREADS + threadIdx.x;
        binrank[i] = -1;
        if (e < E) {
            int s, d;
            if (is64) {
                const long long* p = (const long long*)idx;
                s = (int)p[e]; d = (int)p[(long long)E + e];
            } else {
                const int* p = (const int*)idx;
                s = p[e]; d = p[E + e];
            }
            float w = ew[e];
            int bin = d >> NPB_SHIFT;
            unsigned int pk = ((unsigned)(d & (NPB - 1)) << 23) | (unsigned)s;
            pay[i] = ((unsigned long long)__float_as_uint(w) << 32) | pk;
            int r = atomicAdd(&lcnt[bin], 1);          // LDS atomic (fast)
            binrank[i] = (bin << 16) | r;              // r < 16384 fits 16b
        }
    }
    __syncthreads();
    for (int b = threadIdx.x; b < B; b += PART_THREADS) {
        int c = lcnt[b];
        lbase[b] = (c > 0) ? atomicAdd(&gCnt[b], c) : 0;  // 1 global atomic/(block,bin)
    }
    __syncthreads();
#pragma unroll
    for (int i = 0; i < PART_EPT; ++i) {
        if (binrank[i] >= 0) {
            int bin = binrank[i] >> 16;
            int r = binrank[i] & 0xFFFF;
            long long pos = (long long)lbase[bin] + r;
            if (pos < cap)
                slots[(size_t)bin * cap + pos] = pay[i];
        }
    }
}

// Per-bin: deg[n] = 1 + sum w; dinv = rsqrt(deg); y[n] = x[n]*dinv.
__global__ __launch_bounds__(256)
void k_deg_dinv(const unsigned long long* __restrict__ slots,
                const int* __restrict__ gCnt, const float4* __restrict__ x,
                float* __restrict__ dinv, float4* __restrict__ y,
                int N, int cap) {
    __shared__ float degLds[NPB];
    const int b = blockIdx.x;
    for (int t = threadIdx.x; t < NPB; t += 256) degLds[t] = 0.0f;
    __syncthreads();
    const int c = min(gCnt[b], cap);
    const unsigned long long* sp = slots + (size_t)b * cap;
    for (int j = threadIdx.x; j < c; j += 256) {
        unsigned long long v = sp[j];
        float w = __uint_as_float((unsigned)(v >> 32));
        int dl = (int)(((unsigned)v) >> 23);
        atomicAdd(&degLds[dl], w);
    }
    __syncthreads();
    for (int t = threadIdx.x; t < NPB; t += 256) {
        int n = (b << NPB_SHIFT) + t;
        if (n < N) {
            float di = rsqrtf(1.0f + degLds[t]);
            dinv[n] = di;
            float4 xv = x[n];
            y[n] = make_float4(xv.x * di, xv.y * di, xv.z * di, xv.w * di);
        }
    }
}

// Per-bin layer1 aggregation + fused MLP: z[n] = dinv[n]*MLP(di*(y[n]+sum w*y[s]))
__global__ __launch_bounds__(256)
void k_layer1(const unsigned long long* __restrict__ slots,
              const int* __restrict__ gCnt, const float* __restrict__ dinv,
              const float4* __restrict__ y, const float* __restrict__ W1,
              const float* __restrict__ b1, const float* __restrict__ W2,
              float* __restrict__ z, int N, int cap) {
    __shared__ float acc[NPB][4];
    __shared__ float dLds[NPB];
    __shared__ float sW1[64], sb1[16], sW2[16];
    if (threadIdx.x < 64) sW1[threadIdx.x] = W1[threadIdx.x];
    if (threadIdx.x < 16) {
        sb1[threadIdx.x] = b1[threadIdx.x];
        sW2[threadIdx.x] = W2[threadIdx.x];
    }
    const int b = blockIdx.x;
    for (int t = threadIdx.x; t < NPB; t += 256) {
        acc[t][0] = acc[t][1] = acc[t][2] = acc[t][3] = 0.0f;
        int n = (b << NPB_SHIFT) + t;
        dLds[t] = (n < N) ? dinv[n] : 0.0f;
    }
    __syncthreads();
    const int c = min(gCnt[b], cap);
    const unsigned long long* sp = slots + (size_t)b * cap;
    for (int j = threadIdx.x; j < c; j += 256) {
        unsigned long long v = sp[j];
        float w = __uint_as_float((unsigned)(v >> 32));
        unsigned pk = (unsigned)v;
        int dl = pk >> 23;
        int s = pk & 0x7FFFFF;
        float4 ys = y[s];
        atomicAdd(&acc[dl][0], w * ys.x);
        atomicAdd(&acc[dl][1], w * ys.y);
        atomicAdd(&acc[dl][2], w * ys.z);
        atomicAdd(&acc[dl][3], w * ys.w);
    }
    __syncthreads();
    for (int t = threadIdx.x; t < NPB; t += 256) {
        int n = (b << NPB_SHIFT) + t;
        if (n >= N) continue;
        float di = dLds[t];
        float4 yv = y[n];
        float ax = di * (yv.x + acc[t][0]);
        float ay = di * (yv.y + acc[t][1]);
        float az = di * (yv.z + acc[t][2]);
        float aw = di * (yv.w + acc[t][3]);
        float sacc = 0.0f;
#pragma unroll
        for (int k = 0; k < 16; ++k) {
            float h = ax * sW1[k] + ay * sW1[16 + k] + az * sW1[32 + k]
                    + aw * sW1[48 + k] + sb1[k];
            sacc += fmaxf(h, 0.0f) * sW2[k];
        }
        z[n] = sacc * di;
    }
}

// Per-bin layer2: out[n] = di*(z[n] + sum w*z[s]) + b2
__global__ __launch_bounds__(256)
void k_layer2(const unsigned long long* __restrict__ slots,
              const int* __restrict__ gCnt, const float* __restrict__ dinv,
              const float* __restrict__ z, const float* __restrict__ b2,
              float* __restrict__ out, int N, int cap) {
    __shared__ float acc[NPB];
    __shared__ float dLds[NPB];
    const int b = blockIdx.x;
    for (int t = threadIdx.x; t < NPB; t += 256) {
        acc[t] = 0.0f;
        int n = (b << NPB_SHIFT) + t;
        dLds[t] = (n < N) ? dinv[n] : 0.0f;
    }
    __syncthreads();
    const int c = min(gCnt[b], cap);
    const unsigned long long* sp = slots + (size_t)b * cap;
    for (int j = threadIdx.x; j < c; j += 256) {
        unsigned long long v = sp[j];
        float w = __uint_as_float((unsigned)(v >> 32));
        unsigned pk = (unsigned)v;
        int dl = pk >> 23;
        int s = pk & 0x7FFFFF;
        atomicAdd(&acc[dl], w * z[s]);
    }
    __syncthreads();
    const float bb2 = b2[0];
    for (int t = threadIdx.x; t < NPB; t += 256) {
        int n = (b << NPB_SHIFT) + t;
        if (n < N) out[n] = dLds[t] * (z[n] + acc[t]) + bb2;
    }
}

// ------------------------- fallback (round-1) path -------------------------
__global__ __launch_bounds__(256)
void k_init(float* __restrict__ deg, int N) {
    int i = blockIdx.x * blockDim.x + threadIdx.x;
    if (i < N) deg[i] = 1.0f;
}

__global__ __launch_bounds__(256)
void k_deg(const void* __restrict__ idx, const float* __restrict__ ew,
           float* __restrict__ deg, int E, const int* __restrict__ flag) {
    const bool is64 = (*flag != 0);
    const int stride = gridDim.x * blockDim.x;
    for (int e = blockIdx.x * blockDim.x + threadIdx.x; e < E; e += stride) {
        int d = is64 ? (int)((const long long*)idx)[(long long)E + e]
                     : ((const int*)idx)[E + e];
        atomicAdd(deg + d, ew[e]);
    }
}

__global__ __launch_bounds__(256)
void k_dinv_accx(float* __restrict__ deg_dinv, const float4* __restrict__ x,
                 float4* __restrict__ accx, int N) {
    int n = blockIdx.x * blockDim.x + threadIdx.x;
    if (n >= N) return;
    float dg = deg_dinv[n];
    float di = (dg > 0.0f) ? rsqrtf(dg) : 0.0f;
    deg_dinv[n] = di;
    float sn = di * di;
    float4 xv = x[n];
    accx[n] = make_float4(xv.x * sn, xv.y * sn, xv.z * sn, xv.w * sn);
}

__global__ __launch_bounds__(256)
void k_scatter1(const void* __restrict__ idx, const float* __restrict__ ew,
                const float* __restrict__ dinv, const float4* __restrict__ x,
                float* __restrict__ accx, int E, const int* __restrict__ flag) {
    const bool is64 = (*flag != 0);
    const int stride = gridDim.x * blockDim.x;
    for (int e = blockIdx.x * blockDim.x + threadIdx.x; e < E; e += stride) {
        int s, d;
        if (is64) {
            const long long* p = (const long long*)idx;
            s = (int)p[e]; d = (int)p[(long long)E + e];
        } else {
            const int* p = (const int*)idx;
            s = p[e]; d = p[E + e];
        }
        float nm = dinv[s] * ew[e] * dinv[d];
        float4 xv = x[s];
        float* dp = accx + (size_t)d * 4;
        atomicAdd(dp + 0, nm * xv.x);
        atomicAdd(dp + 1, nm * xv.y);
        atomicAdd(dp + 2, nm * xv.z);
        atomicAdd(dp + 3, nm * xv.w);
    }
}

__global__ __launch_bounds__(256)
void k_node2(const float4* __restrict__ accx, const float* __restrict__ dinv,
             const float* __restrict__ W1, const float* __restrict__ b1,
             const float* __restrict__ W2, const float* __restrict__ b2,
             float* __restrict__ s2, float* __restrict__ out, int N) {
    __shared__ float sW1[64], sb1[16], sW2[16];
    if (threadIdx.x < 64) sW1[threadIdx.x] = W1[threadIdx.x];
    if (threadIdx.x < 16) {
        sb1[threadIdx.x] = b1[threadIdx.x];
        sW2[threadIdx.x] = W2[threadIdx.x];
    }
    __syncthreads();
    int n = blockIdx.x * blockDim.x + threadIdx.x;
    if (n >= N) return;
    float bb2 = b2[0];
    float4 a = accx[n];
    float acc = 0.0f;
#pragma unroll
    for (int k = 0; k < 16; ++k) {
        float h = a.x * sW1[k] + a.y * sW1[16 + k] + a.z * sW1[32 + k]
                + a.w * sW1[48 + k] + sb1[k];
        acc += fmaxf(h, 0.0f) * sW2[k];
    }
    s2[n] = acc;
    float di = dinv[n];
    out[n] = acc * di * di + bb2;
}

__global__ __launch_bounds__(256)
void k_scatter2(const void* __restrict__ idx, const float* __restrict__ ew,
                const float* __restrict__ dinv, const float* __restrict__ s2,
                float* __restrict__ out, int E, const int* __restrict__ flag) {
    const bool is64 = (*flag != 0);
    const int stride = gridDim.x * blockDim.x;
    for (int e = blockIdx.x * blockDim.x + threadIdx.x; e < E; e += stride) {
        int s, d;
        if (is64) {
            const long long* p = (const long long*)idx;
            s = (int)p[e]; d = (int)p[(long long)E + e];
        } else {
            const int* p = (const int*)idx;
            s = p[e]; d = p[E + e];
        }
        float nm = dinv[s] * ew[e] * dinv[d];
        atomicAdd(out + d, nm * s2[s]);
    }
}

// ---------------------------------------------------------------------------
extern "C" void kernel_launch(void* const* d_in, const int* in_sizes, int n_in,
                              void* d_out, int out_size, void* d_ws, size_t ws_size,
                              hipStream_t stream) {
    const float* x   = (const float*)d_in[0];
    const void*  eix = d_in[1];
    const float* ew  = (const float*)d_in[2];
    const float* W1  = (const float*)d_in[3];
    const float* b1  = (const float*)d_in[4];
    const float* W2  = (const float*)d_in[5];
    const float* b2  = (const float*)d_in[6];
    float* out = (float*)d_out;

    const int N = in_sizes[0] / 4;   // x is [N,4]
    const int E = in_sizes[2];       // edge_weight is [E]

    const int B = (N + NPB - 1) >> NPB_SHIFT;
    const int cap = E / B + 2048;    // mean + ~23 sigma headroom
    const int nCheck = (E < 65536) ? E : 65536;

    // ws: y [N float4] | slots [B*cap u64] | gCnt [B] | dinv [N] | z [N] | flag
    size_t need = (size_t)N * 16 + (size_t)B * cap * 8
                + (size_t)B * 4 + (size_t)N * 8 + 256;

    if (B <= MAX_BINS && N < (1 << 23) && ws_size >= need) {
        float4* y = (float4*)d_ws;
        unsigned long long* slots = (unsigned long long*)(y + N);
        int*   gCnt = (int*)(slots + (size_t)B * cap);
        float* dinv = (float*)(gCnt + B);
        float* z    = dinv + N;
        int*   flag = (int*)(z + N);

        const int part_blocks = (E + PART_EPT * PART_THREADS - 1) / (PART_EPT * PART_THREADS);

        k_zero<<<(B + 255) / 256, 256, 0, stream>>>(gCnt, B);
        k_detect<<<1, 1024, 0, stream>>>((const unsigned int*)eix, nCheck, flag);
        k_partition<<<part_blocks, PART_THREADS, 0, stream>>>(eix, ew, gCnt, slots,
                                                              E, B, cap, flag);
        k_deg_dinv<<<B, 256, 0, stream>>>(slots, gCnt, (const float4*)x, dinv, y, N, cap);
        k_layer1<<<B, 256, 0, stream>>>(slots, gCnt, dinv, y, W1, b1, W2, z, N, cap);
        k_layer2<<<B, 256, 0, stream>>>(slots, gCnt, dinv, z, b2, out, N, cap);
    } else {
        // fallback: direct atomic scatter (round-1)
        const int nb_n = (N + 255) / 256;
        const int nb_e = min((E + 255) / 256, 16384);
        float* deg  = (float*)d_ws;
        float* accx = deg + N;
        float* s2   = accx + (size_t)4 * N;
        int*   flag = (int*)(s2 + N);

        k_init<<<nb_n, 256, 0, stream>>>(deg, N);
        k_detect<<<1, 1024, 0, stream>>>((const unsigned int*)eix, nCheck, flag);
        k_deg<<<nb_e, 256, 0, stream>>>(eix, ew, deg, E, flag);
        k_dinv_accx<<<nb_n, 256, 0, stream>>>(deg, (const float4*)x, (float4*)accx, N);
        k_scatter1<<<nb_e, 256, 0, stream>>>(eix, ew, deg, (const float4*)x, accx, E, flag);
        k_node2<<<nb_n, 256, 0, stream>>>((const float4*)accx, deg, W1, b1, W2, b2, s2, out, N);
        k_scatter2<<<nb_e, 256, 0, stream>>>(eix, ew, deg, s2, out, E, flag);
    }
}